// Round 3
// baseline (113.728 us; speedup 1.0000x reference)
//
#include <hip/hip_runtime.h>
#include <hip/hip_bf16.h>

// Elementwise: theta = in + w;  c = cos(theta);  out = {c0, c0*c1} per row.
// Rows are (BATCH, 2) fp32, so one float4 = two complete rows.
// Key change vs prev round: libm cosf (branchy multi-step reduction, was
// ~5x over roofline) -> hardware v_cos_f32 via __builtin_amdgcn_cosf.
// v_cos takes REVOLUTIONS, so fold radians->revolutions into one FMA:
//   cos(x + w) = v_cos(x * INV2PI + w * INV2PI)
// |theta| <= ~7 rad => ~1.1 revolutions, inside v_cos accurate range.
// Accuracy ~1e-6, threshold 2e-2.

#define INV2PI 0.15915494309189535f

__global__ __launch_bounds__(256) void quantum_layer_kernel(
    const float* __restrict__ in,     // BATCH*2 floats
    const float* __restrict__ w,      // 2 floats
    float* __restrict__ out,          // BATCH*2 floats
    int n4)                           // number of float4 chunks = BATCH*2/4
{
    const float w0r = w[0] * INV2PI;
    const float w1r = w[1] * INV2PI;

    const float4* __restrict__ in4 = reinterpret_cast<const float4*>(in);
    float4* __restrict__ out4 = reinterpret_cast<float4*>(out);

    int stride = gridDim.x * blockDim.x;
    for (int i = blockIdx.x * blockDim.x + threadIdx.x; i < n4; i += stride) {
        float4 v = in4[i];
        // v = {row_a.q0, row_a.q1, row_b.q0, row_b.q1}
        float c0a = __builtin_amdgcn_cosf(__builtin_fmaf(v.x, INV2PI, w0r));
        float c1a = __builtin_amdgcn_cosf(__builtin_fmaf(v.y, INV2PI, w1r));
        float c0b = __builtin_amdgcn_cosf(__builtin_fmaf(v.z, INV2PI, w0r));
        float c1b = __builtin_amdgcn_cosf(__builtin_fmaf(v.w, INV2PI, w1r));
        float4 r;
        r.x = c0a;
        r.y = c0a * c1a;
        r.z = c0b;
        r.w = c0b * c1b;
        out4[i] = r;
    }
}

extern "C" void kernel_launch(void* const* d_in, const int* in_sizes, int n_in,
                              void* d_out, int out_size, void* d_ws, size_t ws_size,
                              hipStream_t stream) {
    const float* in = (const float*)d_in[0];
    const float* w  = (const float*)d_in[1];
    float* out      = (float*)d_out;

    int n_elems = in_sizes[0];       // BATCH * 2
    int n4 = n_elems / 4;            // BATCH*2 divisible by 4 (BATCH = 8M)

    const int block = 256;
    int grid = (n4 + block - 1) / block;
    if (grid > 2048) grid = 2048;

    quantum_layer_kernel<<<grid, block, 0, stream>>>(in, w, out, n4);
}

// Round 4
// 111.339 us; speedup vs baseline: 1.0215x; 1.0215x over previous
//
#include <hip/hip_runtime.h>
#include <hip/hip_bf16.h>

// Elementwise: theta = in + w; c = cos(theta); out = {c0, c0*c1} per row.
// Rows are (BATCH, 2) fp32, so one float4 = two complete rows.
// Memory-bound: 64 MiB read + 64 MiB write, floor ~20us at 6.5 TB/s.
// This round: max streaming BW — no grid-stride loop; 8192 blocks x 256 thr,
// 2 independent float4 per thread (32B/lane, 2 loads in flight), contiguous
// per-wave addressing (thread t handles chunk t and t+256 within its block's
// 512-chunk window). HW v_cos_f32 (arg in revolutions, fused via one FMA).

#define INV2PI 0.15915494309189535f

__global__ __launch_bounds__(256) void quantum_layer_kernel(
    const float* __restrict__ in,     // BATCH*2 floats
    const float* __restrict__ w,      // 2 floats
    float* __restrict__ out,          // BATCH*2 floats
    int n4)                           // number of float4 chunks
{
    const float w0r = w[0] * INV2PI;
    const float w1r = w[1] * INV2PI;

    const float4* __restrict__ in4 = reinterpret_cast<const float4*>(in);
    float4* __restrict__ out4 = reinterpret_cast<float4*>(out);

    int i0 = blockIdx.x * 512 + threadIdx.x;   // chunk for load 0
    int i1 = i0 + 256;                         // chunk for load 1

    // Issue both loads before any compute (ILP, 2 dwordx4 in flight).
    float4 va, vb;
    bool p0 = i0 < n4;
    bool p1 = i1 < n4;
    if (p0) va = in4[i0];
    if (p1) vb = in4[i1];

    if (p0) {
        float c0a = __builtin_amdgcn_cosf(__builtin_fmaf(va.x, INV2PI, w0r));
        float c1a = __builtin_amdgcn_cosf(__builtin_fmaf(va.y, INV2PI, w1r));
        float c0b = __builtin_amdgcn_cosf(__builtin_fmaf(va.z, INV2PI, w0r));
        float c1b = __builtin_amdgcn_cosf(__builtin_fmaf(va.w, INV2PI, w1r));
        float4 r;
        r.x = c0a; r.y = c0a * c1a; r.z = c0b; r.w = c0b * c1b;
        out4[i0] = r;
    }
    if (p1) {
        float c0a = __builtin_amdgcn_cosf(__builtin_fmaf(vb.x, INV2PI, w0r));
        float c1a = __builtin_amdgcn_cosf(__builtin_fmaf(vb.y, INV2PI, w1r));
        float c0b = __builtin_amdgcn_cosf(__builtin_fmaf(vb.z, INV2PI, w0r));
        float c1b = __builtin_amdgcn_cosf(__builtin_fmaf(vb.w, INV2PI, w1r));
        float4 r;
        r.x = c0a; r.y = c0a * c1a; r.z = c0b; r.w = c0b * c1b;
        out4[i1] = r;
    }
}

extern "C" void kernel_launch(void* const* d_in, const int* in_sizes, int n_in,
                              void* d_out, int out_size, void* d_ws, size_t ws_size,
                              hipStream_t stream) {
    const float* in = (const float*)d_in[0];
    const float* w  = (const float*)d_in[1];
    float* out      = (float*)d_out;

    int n_elems = in_sizes[0];       // BATCH * 2
    int n4 = n_elems / 4;            // float4 chunks (BATCH*2 divisible by 4)

    const int block = 256;
    const int chunks_per_block = 512;  // 2 float4 per thread
    int grid = (n4 + chunks_per_block - 1) / chunks_per_block;

    quantum_layer_kernel<<<grid, block, 0, stream>>>(in, w, out, n4);
}